// Round 5
// baseline (10796.276 us; speedup 1.0000x reference)
//
#include <hip/hip_runtime.h>

typedef __attribute__((ext_vector_type(8))) short bf16x8;
typedef __attribute__((ext_vector_type(4))) float f32x4;

#define T_LEN 256
// pack offsets (short units)
#define OFF_W1   0
#define OFF_W2   8192
#define OFF_W31  24576
#define OFF_W3   40960
#define OFF_WU1  49152
#define OFF_WR1  65536
#define OFF_WN1  81920
#define OFF_WU2  98304
#define OFF_WR2  106496
#define OFF_WN2  114688
#define OFF_B3W1 131072   // f32[128] appended after bf16 packs
#define PREP_TOT 131200

// LDS layout per group (short units); two groups at gp*GB
#define HA_O   0      // act buffer A [16][128]
#define HB_O   2048   // act buffer B [16][128]; first 1024 doubles as st [16][64]
#define SGH_O  4096   // state hi / Gsum lo [16][128]
#define SGL_O  6144   // state lo [16][128]
#define FU_F   4096   // float-index within group: u gate f32 [16][64]
#define FR_F   5120   // float-index within group: r gate f32 [16][64]
#define GB     12288  // shorts per group block
#define FGAP   6144   // float units per group block

__device__ __forceinline__ unsigned short bf16r(float f){
  unsigned int x = __builtin_bit_cast(unsigned int, f);
  unsigned int r = (x + 0x7FFFu + ((x >> 16) & 1u)) >> 16;
  return (unsigned short)r;
}
__device__ __forceinline__ float bf16tof(unsigned short u){
  unsigned int v = ((unsigned int)u) << 16;
  return __builtin_bit_cast(float, v);
}
__device__ __forceinline__ float fast_tanh(float x){
  float e = __builtin_amdgcn_exp2f(x * 2.885390081777927f);   // exp(2x)
  return 1.0f - 2.0f * __builtin_amdgcn_rcpf(1.0f + e);
}
__device__ __forceinline__ float fast_sigmoid(float x){
  float e = __builtin_amdgcn_exp2f(x * -1.4426950408889634f); // exp(-x)
  return __builtin_amdgcn_rcpf(1.0f + e);
}
__device__ __forceinline__ f32x4 mfma16(bf16x8 a, bf16x8 b, f32x4 c){
  return __builtin_amdgcn_mfma_f32_16x16x32_bf16(a, b, c, 0, 0, 0);
}
__device__ __forceinline__ bf16x8 load_bfrag(const unsigned short* p, int blk, int lane){
  return *reinterpret_cast<const bf16x8*>(p + ((blk << 6) + lane) * 8);
}
__device__ __forceinline__ bf16x8 ldsA(const unsigned short* LDSU, int idx){
  return *reinterpret_cast<const bf16x8*>(LDSU + idx);
}

// Pack weights to bf16 MFMA B-fragment order; compute W31=W3@W1, b3W1=b3@W1.
__global__ void prep_pack(const float* __restrict__ W1, const float* __restrict__ W2,
                          const float* __restrict__ W3, const float* __restrict__ Wu1,
                          const float* __restrict__ Wr1, const float* __restrict__ Wn1,
                          const float* __restrict__ Wu2, const float* __restrict__ Wr2,
                          const float* __restrict__ Wn2, const float* __restrict__ b3,
                          unsigned short* __restrict__ pack)
{
  int e = blockIdx.x * blockDim.x + threadIdx.x;
  if (e >= PREP_TOT) return;
  if (e >= OFF_B3W1){
    int j = e - OFF_B3W1;           // 0..127
    float s = 0.0f;
    for (int mm = 0; mm < 64; ++mm) s += b3[mm] * W1[mm * 128 + j];
    ((float*)(pack + OFF_B3W1))[j] = s;
    return;
  }
  const int offs[11] = {0, 8192, 24576, 40960, 49152, 65536, 81920, 98304, 106496, 114688, 131072};
  const int Ks[10] = {64,128,128,128,128,128,128,128,128,128};
  const int Ns[10] = {128,128,128,64,128,128,128,64,64,128};
  int m = 0;
  while (e >= offs[m + 1]) ++m;
  int el = e - offs[m];
  int j = el & 7, lane = (el >> 3) & 63, blk = el >> 9;
  int ksteps = Ks[m] >> 5;
  int ks = blk % ksteps, nt = blk / ksteps;
  int k = ks * 32 + ((lane >> 4) << 3) + j;
  int n = nt * 16 + (lane & 15);
  float v;
  if (m == 2){ // W31[k][n] = sum_mm W3[k][mm] * W1[mm][n]
    float s = 0.0f;
    for (int mm = 0; mm < 64; ++mm) s += W3[k * 64 + mm] * W1[mm * 128 + n];
    v = s;
  } else {
    const float* srcs[10] = {W1, W2, nullptr, W3, Wu1, Wr1, Wn1, Wu2, Wr2, Wn2};
    v = srcs[m][k * Ns[m] + n];
  }
  pack[e] = bf16r(v);
}

__global__ __launch_bounds__(512, 2) void ode_rnn_main(
  const float* __restrict__ bts, const float* __restrict__ mtr,
  const float* __restrict__ b1, const float* __restrict__ b2, const float* __restrict__ b3,
  const float* __restrict__ bu1, const float* __restrict__ bu2,
  const float* __restrict__ br1, const float* __restrict__ br2,
  const float* __restrict__ bn1, const float* __restrict__ bn2,
  const float* __restrict__ Wu1f, const float* __restrict__ Wr1f, const float* __restrict__ Wn1f,
  const unsigned short* __restrict__ pack, float* __restrict__ out)
{
  __shared__ __align__(16) unsigned short LDSU[2 * GB];
  float* FUR = (float*)LDSU;
  const int tid = threadIdx.x, w = tid >> 6, lane = tid & 63;
  const int arow = lane & 15, g = lane >> 4, rb = g << 2;
  const int c128 = (w << 4) + arow;
  const int c64  = ((w & 3) << 4) + arow;
  const bool isMean = (w < 4);
  const int rowBase = blockIdx.x * 32;

  // precomputed LDS indices (short units)
  int a128[4], wr128[4], wr64[4], furi[4], a64v[2];
#pragma unroll
  for (int ks = 0; ks < 4; ++ks) a128[ks] = arow*128 + ((32*ks + 8*g) ^ (arow << 3));
#pragma unroll
  for (int ks = 0; ks < 2; ++ks) a64v[ks] = arow*64 + ((32*ks + 8*g) ^ ((arow & 7) << 3));
#pragma unroll
  for (int i = 0; i < 4; ++i){
    int r = rb + i;
    wr128[i] = r*128 + (c128 ^ (r << 3));
    wr64[i]  = r*64  + (c64 ^ ((r & 7) << 3));
    furi[i]  = r*64 + c64;
  }

  // persistent per-wave weight fragments (hoisted; ~104 VGPR)
  bf16x8 w1f[2], w2f[4], w31f[4], w3f[4], wu1w[4], wr1w[4], wn1w[4];
#pragma unroll
  for (int ks = 0; ks < 2; ++ks) w1f[ks]  = load_bfrag(pack + OFF_W1,  2*w + ks, lane);
#pragma unroll
  for (int ks = 0; ks < 4; ++ks){
    w2f[ks]  = load_bfrag(pack + OFF_W2,  4*w + ks, lane);
    w31f[ks] = load_bfrag(pack + OFF_W31, 4*w + ks, lane);
    w3f[ks]  = load_bfrag(pack + OFF_W3,  4*(w & 3) + ks, lane);
    wu1w[ks] = load_bfrag(pack + OFF_WU1, 4*w + ks, lane);
    wr1w[ks] = load_bfrag(pack + OFF_WR1, 4*w + ks, lane);
    wn1w[ks] = load_bfrag(pack + OFF_WN1, 4*w + ks, lane);
  }

  const float* b3w1p = (const float*)(pack + OFF_B3W1);
  const float b1c = b1[c128], b2c = b2[c128], b3c = b3[c64], b3w1c = b3w1p[c128];
  const float bu1c = bu1[c128], br1c = br1[c128], bn1c = bn1[c128], bn2c = bn2[c128];
  const float g2b = isMean ? bu2[c64] : br2[c64];
  const float wu1L = Wu1f[16384 + c128], wr1L = Wr1f[16384 + c128], wn1L = Wn1f[16384 + c128];

  // zero st buffers (both groups)
  ((unsigned long long*)(LDSU + HB_O))[tid] = 0ULL;
  ((unsigned long long*)(LDSU + GB + HB_O))[tid] = 0ULL;
  __syncthreads();

  f32x4 st[2], R[2], yf[2], u[2];
#pragma unroll
  for (int gp = 0; gp < 2; ++gp){
    st[gp] = (f32x4){0.f,0.f,0.f,0.f}; R[gp] = (f32x4){0.f,0.f,0.f,0.f};
    yf[gp] = (f32x4){0.f,0.f,0.f,0.f}; u[gp] = (f32x4){0.f,0.f,0.f,0.f};
  }

#pragma unroll 1
  for (int s = 0; s < T_LEN; ++s){
    const int tj = T_LEN - 1 - s;
    const float t1 = bts[2*tj];
    const float t0 = (s == 0) ? 5.0f : bts[2*tj + 2];
    const float hh = (t1 - t0) * 0.125f;

    f32x4 xr[2], mk[2];
#pragma unroll
    for (int gp = 0; gp < 2; ++gp)
#pragma unroll
      for (int i = 0; i < 4; ++i)
        xr[gp][i] = bts[((rowBase + 16*gp + rb + i) * T_LEN + tj) * 2 + 1];

    f32x4 Gsum[2], Hsum[2];
#pragma unroll
    for (int gp = 0; gp < 2; ++gp) Gsum[gp] = (f32x4){0.f,0.f,0.f,0.f};

    // ---------------- RK4: 8 substeps x 8 phases, 2 groups each ----------------
#pragma unroll 1
    for (int ss = 0; ss < 8; ++ss){
      // ---- p0: h1_1 (+ R recurrence) ----
#pragma unroll
      for (int gp = 0; gp < 2; ++gp){
        unsigned short* L = LDSU + gp*GB;
        f32x4 acc;
        if (ss == 0){
          acc = (f32x4){b1c, b1c, b1c, b1c};
          acc = mfma16(ldsA(L, HB_O + a64v[0]), w1f[0], acc);
          acc = mfma16(ldsA(L, HB_O + a64v[1]), w1f[1], acc);
        } else {
#pragma unroll
          for (int i = 0; i < 4; ++i) acc[i] = R[gp][i] + hh * b3w1c;
#pragma unroll
          for (int ks = 0; ks < 4; ++ks)
            acc = mfma16(ldsA(L, HB_O + a128[ks]), w31f[ks], acc);
        }
        R[gp] = acc;
#pragma unroll
        for (int i = 0; i < 4; ++i) L[HA_O + wr128[i]] = bf16r(fast_tanh(acc[i]));
      }
      __syncthreads();
      // ---- p1/p3/p5 (h2 stages 1..3) + p2/p4/p6 (h1 stages 2..4) ----
#pragma unroll
      for (int hs = 0; hs < 3; ++hs){
        const float wgt = (hs == 0) ? 1.0f : 2.0f;
        const float scn = (hs == 2) ? hh : 0.5f * hh;
#pragma unroll
        for (int gp = 0; gp < 2; ++gp){
          unsigned short* L = LDSU + gp*GB;
          f32x4 acc = (f32x4){b2c, b2c, b2c, b2c};
#pragma unroll
          for (int ks = 0; ks < 4; ++ks)
            acc = mfma16(ldsA(L, HA_O + a128[ks]), w2f[ks], acc);
          f32x4 h;
#pragma unroll
          for (int i = 0; i < 4; ++i) h[i] = fast_tanh(acc[i]);
          if (hs == 0) Hsum[gp] = h;
          else {
#pragma unroll
            for (int i = 0; i < 4; ++i) Hsum[gp][i] += wgt * h[i];
          }
#pragma unroll
          for (int i = 0; i < 4; ++i) L[HB_O + wr128[i]] = bf16r(h[i] * scn);
        }
        __syncthreads();
        const float ac = (hs == 2) ? hh : 0.5f * hh;
#pragma unroll
        for (int gp = 0; gp < 2; ++gp){
          unsigned short* L = LDSU + gp*GB;
          f32x4 acc2;
#pragma unroll
          for (int i = 0; i < 4; ++i) acc2[i] = R[gp][i] + ac * b3w1c;
#pragma unroll
          for (int ks = 0; ks < 4; ++ks)
            acc2 = mfma16(ldsA(L, HB_O + a128[ks]), w31f[ks], acc2);
#pragma unroll
          for (int i = 0; i < 4; ++i) L[HA_O + wr128[i]] = bf16r(fast_tanh(acc2[i]));
        }
        __syncthreads();
      }
      // ---- p7: h2_4, Hsum/Gsum finalize ----
#pragma unroll
      for (int gp = 0; gp < 2; ++gp){
        unsigned short* L = LDSU + gp*GB;
        f32x4 acc = (f32x4){b2c, b2c, b2c, b2c};
#pragma unroll
        for (int ks = 0; ks < 4; ++ks)
          acc = mfma16(ldsA(L, HA_O + a128[ks]), w2f[ks], acc);
        f32x4 h;
#pragma unroll
        for (int i = 0; i < 4; ++i){ h[i] = fast_tanh(acc[i]); Hsum[gp][i] += h[i]; Gsum[gp][i] += Hsum[gp][i]; }
        const float sc6 = hh * (1.0f / 6.0f);
        if (ss < 7){
#pragma unroll
          for (int i = 0; i < 4; ++i) L[HB_O + wr128[i]] = bf16r(Hsum[gp][i] * sc6);
        } else {
#pragma unroll
          for (int i = 0; i < 4; ++i){
            float gv = Gsum[gp][i] * sc6;
            unsigned short hi = bf16r(gv);
            L[HB_O  + wr128[i]] = hi;
            L[SGH_O + wr128[i]] = bf16r(gv - bf16tof(hi));
          }
        }
      }
      __syncthreads();
    }

    // ---------------- phase Y: recover mean_ode (mean waves) ----------------
    if (isMean){
#pragma unroll
      for (int gp = 0; gp < 2; ++gp){
        const unsigned short* L = LDSU + gp*GB;
        f32x4 acc = {0.f,0.f,0.f,0.f};
#pragma unroll
        for (int ks = 0; ks < 4; ++ks) acc = mfma16(ldsA(L, HB_O  + a128[ks]), w3f[ks], acc);
#pragma unroll
        for (int ks = 0; ks < 4; ++ks) acc = mfma16(ldsA(L, SGH_O + a128[ks]), w3f[ks], acc);
#pragma unroll
        for (int i = 0; i < 4; ++i) yf[gp][i] = st[gp][i] + acc[i] + 8.0f * hh * b3c;
      }
    }
    __syncthreads();
    // ---------------- phase Y2: write state hi/lo ----------------
#pragma unroll
    for (int gp = 0; gp < 2; ++gp){
      unsigned short* L = LDSU + gp*GB;
      f32x4 sv = isMean ? yf[gp] : st[gp];
#pragma unroll
      for (int i = 0; i < 4; ++i){
        unsigned short hi = bf16r(sv[i]);
        L[SGH_O + wr128[i]] = hi;
        L[SGL_O + wr128[i]] = bf16r(sv[i] - bf16tof(hi));
      }
    }
    __syncthreads();
    // ---------------- GRU g1: u & r first layers ----------------
#pragma unroll
    for (int gp = 0; gp < 2; ++gp){
      unsigned short* L = LDSU + gp*GB;
      f32x4 au = {0.f,0.f,0.f,0.f}, ar = {0.f,0.f,0.f,0.f};
#pragma unroll
      for (int ks = 0; ks < 4; ++ks){
        bf16x8 ah = ldsA(L, SGH_O + a128[ks]);
        bf16x8 al = ldsA(L, SGL_O + a128[ks]);
        au = mfma16(al, wu1w[ks], au); au = mfma16(ah, wu1w[ks], au);
        ar = mfma16(al, wr1w[ks], ar); ar = mfma16(ah, wr1w[ks], ar);
      }
#pragma unroll
      for (int i = 0; i < 4; ++i){
        au[i] = fast_tanh(au[i] + bu1c + xr[gp][i] * wu1L);
        ar[i] = fast_tanh(ar[i] + br1c + xr[gp][i] * wr1L);
      }
#pragma unroll
      for (int i = 0; i < 4; ++i){
        L[HA_O + wr128[i]] = bf16r(au[i]);
        L[HB_O + wr128[i]] = bf16r(ar[i]);
      }
    }
    __syncthreads();
    // ---------------- GRU g2: second layers (mean->u, std->r) ----------------
    f32x4 rr[2];
    {
      bf16x8 g2w[4];
      const int pb = isMean ? OFF_WU2 : OFF_WR2;
#pragma unroll
      for (int ks = 0; ks < 4; ++ks) g2w[ks] = load_bfrag(pack + pb, 4*(w & 3) + ks, lane);
#pragma unroll
      for (int gp = 0; gp < 2; ++gp){
        const unsigned short* L = LDSU + gp*GB;
        const int srcO = isMean ? HA_O : HB_O;
        f32x4 acc = {0.f,0.f,0.f,0.f};
#pragma unroll
        for (int ks = 0; ks < 4; ++ks)
          acc = mfma16(ldsA(L, srcO + a128[ks]), g2w[ks], acc);
        if (isMean){
#pragma unroll
          for (int i = 0; i < 4; ++i){ u[gp][i] = fast_sigmoid(acc[i] + g2b); FUR[gp*FGAP + FU_F + furi[i]] = u[gp][i]; }
        } else {
#pragma unroll
          for (int i = 0; i < 4; ++i){ rr[gp][i] = fast_sigmoid(acc[i] + g2b); FUR[gp*FGAP + FR_F + furi[i]] = rr[gp][i]; }
        }
      }
    }
#pragma unroll
    for (int gp = 0; gp < 2; ++gp)
#pragma unroll
      for (int i = 0; i < 4; ++i)
        mk[gp][i] = mtr[(rowBase + 16*gp + rb + i) * T_LEN + tj];
    __syncthreads();
    // ---------------- GRU g3: gated state -> SGH/SGL ----------------
#pragma unroll
    for (int gp = 0; gp < 2; ++gp){
      unsigned short* L = LDSU + gp*GB;
      f32x4 yc;
      if (isMean){
#pragma unroll
        for (int i = 0; i < 4; ++i){ float r_ = FUR[gp*FGAP + FR_F + furi[i]]; yc[i] = yf[gp][i] * r_; }
      } else {
#pragma unroll
        for (int i = 0; i < 4; ++i){ u[gp][i] = FUR[gp*FGAP + FU_F + furi[i]]; yc[i] = st[gp][i] * rr[gp][i]; }
      }
#pragma unroll
      for (int i = 0; i < 4; ++i){
        unsigned short hi = bf16r(yc[i]);
        L[SGH_O + wr128[i]] = hi;
        L[SGL_O + wr128[i]] = bf16r(yc[i] - bf16tof(hi));
      }
    }
    __syncthreads();
    // ---------------- GRU g4: n first layer ----------------
#pragma unroll
    for (int gp = 0; gp < 2; ++gp){
      unsigned short* L = LDSU + gp*GB;
      f32x4 an = {0.f,0.f,0.f,0.f};
#pragma unroll
      for (int ks = 0; ks < 4; ++ks){
        bf16x8 ah = ldsA(L, SGH_O + a128[ks]);
        bf16x8 al = ldsA(L, SGL_O + a128[ks]);
        an = mfma16(al, wn1w[ks], an); an = mfma16(ah, wn1w[ks], an);
      }
#pragma unroll
      for (int i = 0; i < 4; ++i) an[i] = fast_tanh(an[i] + bn1c + xr[gp][i] * wn1L);
#pragma unroll
      for (int i = 0; i < 4; ++i) L[HA_O + wr128[i]] = bf16r(an[i]);
    }
    __syncthreads();
    // ---------------- GRU g5: n second layer + blend ----------------
    {
      bf16x8 n2w[4];
#pragma unroll
      for (int ks = 0; ks < 4; ++ks) n2w[ks] = load_bfrag(pack + OFF_WN2, 4*w + ks, lane);
#pragma unroll
      for (int gp = 0; gp < 2; ++gp){
        unsigned short* L = LDSU + gp*GB;
        f32x4 ns = {0.f,0.f,0.f,0.f};
#pragma unroll
        for (int ks = 0; ks < 4; ++ks)
          ns = mfma16(ldsA(L, HA_O + a128[ks]), n2w[ks], ns);
#pragma unroll
        for (int i = 0; i < 4; ++i){
          float nv = ns[i] + bn2c;
          float uu = u[gp][i];
          float base = isMean ? yf[gp][i] : st[gp][i];
          float nm = (1.0f - uu) * nv + uu * base;
          float fs = mk[gp][i] * nm + (1.0f - mk[gp][i]) * base;
          st[gp][i] = isMean ? fs : fabsf(fs);
        }
        if (isMean){
#pragma unroll
          for (int i = 0; i < 4; ++i) L[HB_O + wr64[i]] = bf16r(st[gp][i]);
        }
      }
    }
    __syncthreads();
  }

  // ---------------- store ----------------
#pragma unroll
  for (int gp = 0; gp < 2; ++gp)
#pragma unroll
    for (int i = 0; i < 4; ++i){
      int r = rowBase + 16*gp + rb + i;
      if (isMean) out[r * 64 + c64] = st[gp][i];
      else        out[524288 + r * 64 + c64] = st[gp][i];
    }
}

extern "C" void kernel_launch(void* const* d_in, const int* in_sizes, int n_in,
                              void* d_out, int out_size, void* d_ws, size_t ws_size,
                              hipStream_t stream)
{
  (void)in_sizes; (void)n_in; (void)out_size; (void)ws_size;
  unsigned short* pack = (unsigned short*)d_ws;
  prep_pack<<<dim3((PREP_TOT + 255) / 256), dim3(256), 0, stream>>>(
      (const float*)d_in[2],  (const float*)d_in[4],  (const float*)d_in[6],
      (const float*)d_in[8],  (const float*)d_in[12], (const float*)d_in[16],
      (const float*)d_in[10], (const float*)d_in[14], (const float*)d_in[18],
      (const float*)d_in[7],  pack);
  ode_rnn_main<<<dim3(256), dim3(512), 0, stream>>>(
      (const float*)d_in[0],  (const float*)d_in[1],
      (const float*)d_in[3],  (const float*)d_in[5],  (const float*)d_in[7],
      (const float*)d_in[9],  (const float*)d_in[11],
      (const float*)d_in[13], (const float*)d_in[15],
      (const float*)d_in[17], (const float*)d_in[19],
      (const float*)d_in[8],  (const float*)d_in[12], (const float*)d_in[16],
      (const unsigned short*)pack, (float*)d_out);
}

// Round 6
// 4503.886 us; speedup vs baseline: 2.3971x; 2.3971x over previous
//
#include <hip/hip_runtime.h>

typedef __attribute__((ext_vector_type(8))) short bf16x8;
typedef __attribute__((ext_vector_type(4))) float f32x4;

#define T_LEN 256
// pack offsets (short units)
#define OFF_W1   0
#define OFF_W2   8192
#define OFF_W31  24576
#define OFF_W3   40960
#define OFF_WU1  49152
#define OFF_WR1  65536
#define OFF_WN1  81920
#define OFF_WU2  98304
#define OFF_WR2  106496
#define OFF_WN2  114688
#define OFF_B3W1 131072   // f32[128] appended after bf16 packs
#define PREP_TOT 131200

// LDS layout (short units)
#define HA_O   0      // act buffer A [16][128]; also state-hi after Y
#define HB_O   2048   // act buffer B [16][128]; first 1024 doubles as st-mean [16][64]
#define SGH_O  4096   // h2-scaled / Gsum-lo / r1-act / yc-lo [16][128]
#define SGL_O  6144   // state lo [16][128]
#define FU_F   4096   // float-index: u gate f32 [16][64]  (shorts 8192..10239)
#define FR_F   5120   // float-index: r gate f32 [16][64]  (shorts 10240..12287)
#define LDS_SHORTS 12288

__device__ __forceinline__ unsigned short bf16r(float f){
  unsigned int x = __builtin_bit_cast(unsigned int, f);
  unsigned int r = (x + 0x7FFFu + ((x >> 16) & 1u)) >> 16;
  return (unsigned short)r;
}
__device__ __forceinline__ float bf16tof(unsigned short u){
  unsigned int v = ((unsigned int)u) << 16;
  return __builtin_bit_cast(float, v);
}
__device__ __forceinline__ float fast_tanh(float x){
  float e = __builtin_amdgcn_exp2f(x * 2.885390081777927f);   // exp(2x)
  return 1.0f - 2.0f * __builtin_amdgcn_rcpf(1.0f + e);
}
__device__ __forceinline__ float fast_sigmoid(float x){
  float e = __builtin_amdgcn_exp2f(x * -1.4426950408889634f); // exp(-x)
  return __builtin_amdgcn_rcpf(1.0f + e);
}
__device__ __forceinline__ f32x4 mfma16(bf16x8 a, bf16x8 b, f32x4 c){
  return __builtin_amdgcn_mfma_f32_16x16x32_bf16(a, b, c, 0, 0, 0);
}
__device__ __forceinline__ bf16x8 load_bfrag(const unsigned short* p, int blk, int lane){
  return *reinterpret_cast<const bf16x8*>(p + ((blk << 6) + lane) * 8);
}
__device__ __forceinline__ bf16x8 ldsA(const unsigned short* LDSU, int idx){
  return *reinterpret_cast<const bf16x8*>(LDSU + idx);
}

// Pack weights to bf16 MFMA B-fragment order; compute W31=W3@W1, b3W1=b3@W1.
__global__ void prep_pack(const float* __restrict__ W1, const float* __restrict__ W2,
                          const float* __restrict__ W3, const float* __restrict__ Wu1,
                          const float* __restrict__ Wr1, const float* __restrict__ Wn1,
                          const float* __restrict__ Wu2, const float* __restrict__ Wr2,
                          const float* __restrict__ Wn2, const float* __restrict__ b3,
                          unsigned short* __restrict__ pack)
{
  int e = blockIdx.x * blockDim.x + threadIdx.x;
  if (e >= PREP_TOT) return;
  if (e >= OFF_B3W1){
    int j = e - OFF_B3W1;           // 0..127
    float s = 0.0f;
    for (int mm = 0; mm < 64; ++mm) s += b3[mm] * W1[mm * 128 + j];
    ((float*)(pack + OFF_B3W1))[j] = s;
    return;
  }
  const int offs[11] = {0, 8192, 24576, 40960, 49152, 65536, 81920, 98304, 106496, 114688, 131072};
  const int Ks[10] = {64,128,128,128,128,128,128,128,128,128};
  const int Ns[10] = {128,128,128,64,128,128,128,64,64,128};
  int m = 0;
  while (e >= offs[m + 1]) ++m;
  int el = e - offs[m];
  int j = el & 7, lane = (el >> 3) & 63, blk = el >> 9;
  int ksteps = Ks[m] >> 5;
  int ks = blk % ksteps, nt = blk / ksteps;
  int k = ks * 32 + ((lane >> 4) << 3) + j;
  int n = nt * 16 + (lane & 15);
  float v;
  if (m == 2){ // W31[k][n] = sum_mm W3[k][mm] * W1[mm][n]
    float s = 0.0f;
    for (int mm = 0; mm < 64; ++mm) s += W3[k * 64 + mm] * W1[mm * 128 + n];
    v = s;
  } else {
    const float* srcs[10] = {W1, W2, nullptr, W3, Wu1, Wr1, Wn1, Wu2, Wr2, Wn2};
    v = srcs[m][k * Ns[m] + n];
  }
  pack[e] = bf16r(v);
}

__global__ __launch_bounds__(512, 4) void ode_rnn_main(
  const float* __restrict__ bts, const float* __restrict__ mtr,
  const float* __restrict__ b1, const float* __restrict__ b2, const float* __restrict__ b3,
  const float* __restrict__ bu1, const float* __restrict__ bu2,
  const float* __restrict__ br1, const float* __restrict__ br2,
  const float* __restrict__ bn1, const float* __restrict__ bn2,
  const float* __restrict__ Wu1f, const float* __restrict__ Wr1f, const float* __restrict__ Wn1f,
  const unsigned short* __restrict__ pack, float* __restrict__ out)
{
  __shared__ __align__(16) unsigned short LDSU[LDS_SHORTS];
  float* FUR = (float*)LDSU;
  const int tid = threadIdx.x, w = tid >> 6, lane = tid & 63;
  const int arow = lane & 15, g = lane >> 4, rb = g << 2;
  const int c128 = (w << 4) + arow;        // wave's 128-wide column (== state column)
  const int c64  = ((w & 3) << 4) + arow;  // wave's 64-wide column
  const bool isMean = (w < 4);
  const int rowBase = blockIdx.x * 16;

  // precomputed LDS indices (short units)
  int a128[4], wr128[4], wr64[4], furi[4], a64v[2];
#pragma unroll
  for (int ks = 0; ks < 4; ++ks) a128[ks] = arow*128 + ((32*ks + 8*g) ^ (arow << 3));
#pragma unroll
  for (int ks = 0; ks < 2; ++ks) a64v[ks] = arow*64 + ((32*ks + 8*g) ^ ((arow & 7) << 3));
#pragma unroll
  for (int i = 0; i < 4; ++i){
    int r = rb + i;
    wr128[i] = r*128 + (c128 ^ (r << 3));
    wr64[i]  = r*64  + (c64 ^ ((r & 7) << 3));
    furi[i]  = r*64 + c64;
  }

  // persistent per-wave weight fragments
  bf16x8 w1f[2], w2f[4], w31f[4];
#pragma unroll
  for (int ks = 0; ks < 2; ++ks) w1f[ks]  = load_bfrag(pack + OFF_W1,  2*w + ks, lane);
#pragma unroll
  for (int ks = 0; ks < 4; ++ks) w2f[ks]  = load_bfrag(pack + OFF_W2,  4*w + ks, lane);
#pragma unroll
  for (int ks = 0; ks < 4; ++ks) w31f[ks] = load_bfrag(pack + OFF_W31, 4*w + ks, lane);

  const float* b3w1p = (const float*)(pack + OFF_B3W1);
  const float b1c = b1[c128], b2c = b2[c128], b3c = b3[c64], b3w1c = b3w1p[c128];
  const float bu1c = bu1[c128], br1c = br1[c128], bn1c = bn1[c128], bn2c = bn2[c128];
  const float g2b = isMean ? bu2[c64] : br2[c64];
  const float wu1L = Wu1f[16384 + c128], wr1L = Wr1f[16384 + c128], wn1L = Wn1f[16384 + c128];

  // zero st buffer (HB[0:2048])
  ((unsigned long long*)(LDSU + HB_O))[tid] = 0ULL;
  __syncthreads();

  f32x4 st = {0.f,0.f,0.f,0.f};   // w<4: mean state; w>=4: std state
  f32x4 yf = {0.f,0.f,0.f,0.f};   // mean_ode (mean waves)
  f32x4 u  = {0.f,0.f,0.f,0.f};

#pragma unroll 1
  for (int s = 0; s < T_LEN; ++s){
    const int tj = T_LEN - 1 - s;
    const float t1 = bts[2*tj];
    const float t0 = (s == 0) ? 5.0f : bts[2*tj + 2];
    const float hh = (t1 - t0);            // single RK4 step over the whole interval

    f32x4 xr;
#pragma unroll
    for (int i = 0; i < 4; ++i) xr[i] = bts[((rowBase + rb + i) * T_LEN + tj) * 2 + 1];

    f32x4 Hsum, R;

    // ---------------- RK4: ONE substep, 8 phases ----------------
    // p0: h1 of stage 1 (from mean state, K=64)
    {
      f32x4 acc = (f32x4){b1c, b1c, b1c, b1c};
      acc = mfma16(ldsA(LDSU, HB_O + a64v[0]), w1f[0], acc);
      acc = mfma16(ldsA(LDSU, HB_O + a64v[1]), w1f[1], acc);
      R = acc;
#pragma unroll
      for (int i = 0; i < 4; ++i) LDSU[HA_O + wr128[i]] = bf16r(fast_tanh(acc[i]));
    }
    __syncthreads();
    // p1/p3/p5 (h2 stages 1..3) + p2/p4/p6 (h1 stages 2..4)
#pragma unroll
    for (int hs = 0; hs < 3; ++hs){
      const float wgt = (hs == 0) ? 1.0f : 2.0f;
      const float scn = (hs == 2) ? hh : 0.5f * hh;
      {
        f32x4 acc = (f32x4){b2c, b2c, b2c, b2c};
#pragma unroll
        for (int ks = 0; ks < 4; ++ks)
          acc = mfma16(ldsA(LDSU, HA_O + a128[ks]), w2f[ks], acc);
        f32x4 h;
#pragma unroll
        for (int i = 0; i < 4; ++i) h[i] = fast_tanh(acc[i]);
        if (hs == 0) Hsum = h;
        else {
#pragma unroll
          for (int i = 0; i < 4; ++i) Hsum[i] += wgt * h[i];
        }
#pragma unroll
        for (int i = 0; i < 4; ++i) LDSU[SGH_O + wr128[i]] = bf16r(h[i] * scn);
      }
      __syncthreads();
      {
        const float ac = (hs == 2) ? hh : 0.5f * hh;
        f32x4 acc2;
#pragma unroll
        for (int i = 0; i < 4; ++i) acc2[i] = R[i] + ac * b3w1c;
#pragma unroll
        for (int ks = 0; ks < 4; ++ks)
          acc2 = mfma16(ldsA(LDSU, SGH_O + a128[ks]), w31f[ks], acc2);
#pragma unroll
        for (int i = 0; i < 4; ++i) LDSU[HA_O + wr128[i]] = bf16r(fast_tanh(acc2[i]));
      }
      __syncthreads();
    }
    // p7: h2 stage 4, finalize Gsum (= Hsum) hi/lo -> HB/SGH
    {
      f32x4 acc = (f32x4){b2c, b2c, b2c, b2c};
#pragma unroll
      for (int ks = 0; ks < 4; ++ks)
        acc = mfma16(ldsA(LDSU, HA_O + a128[ks]), w2f[ks], acc);
      const float sc6 = hh * (1.0f / 6.0f);
#pragma unroll
      for (int i = 0; i < 4; ++i){
        float h = fast_tanh(acc[i]);
        float gv = (Hsum[i] + h) * sc6;
        unsigned short hi = bf16r(gv);
        LDSU[HB_O  + wr128[i]] = hi;
        LDSU[SGH_O + wr128[i]] = bf16r(gv - bf16tof(hi));
      }
    }
    __syncthreads();
    // ---------------- phase Y: recover mean_ode + write state hi/lo -> HA/SGL ----------------
    if (isMean){
      bf16x8 w3f[4];
#pragma unroll
      for (int ks = 0; ks < 4; ++ks) w3f[ks] = load_bfrag(pack + OFF_W3, 4*w + ks, lane);
      f32x4 acc = {0.f,0.f,0.f,0.f};
#pragma unroll
      for (int ks = 0; ks < 4; ++ks) acc = mfma16(ldsA(LDSU, HB_O  + a128[ks]), w3f[ks], acc);
#pragma unroll
      for (int ks = 0; ks < 4; ++ks) acc = mfma16(ldsA(LDSU, SGH_O + a128[ks]), w3f[ks], acc);
#pragma unroll
      for (int i = 0; i < 4; ++i) yf[i] = st[i] + acc[i] + hh * b3c;
#pragma unroll
      for (int i = 0; i < 4; ++i){
        unsigned short hi = bf16r(yf[i]);
        LDSU[HA_O  + wr128[i]] = hi;
        LDSU[SGL_O + wr128[i]] = bf16r(yf[i] - bf16tof(hi));
      }
    } else {
#pragma unroll
      for (int i = 0; i < 4; ++i){
        unsigned short hi = bf16r(st[i]);
        LDSU[HA_O  + wr128[i]] = hi;
        LDSU[SGL_O + wr128[i]] = bf16r(st[i] - bf16tof(hi));
      }
    }
    __syncthreads();
    // ---------------- GRU g1: u & r first layers (read HA/SGL, write HB/SGH) ----------------
    {
      f32x4 au = {0.f,0.f,0.f,0.f}, ar = {0.f,0.f,0.f,0.f};
#pragma unroll
      for (int ks = 0; ks < 4; ++ks){
        bf16x8 ah = ldsA(LDSU, HA_O  + a128[ks]);
        bf16x8 al = ldsA(LDSU, SGL_O + a128[ks]);
        bf16x8 bu = load_bfrag(pack + OFF_WU1, 4*w + ks, lane);
        bf16x8 br_ = load_bfrag(pack + OFF_WR1, 4*w + ks, lane);
        au = mfma16(al, bu, au);  au = mfma16(ah, bu, au);
        ar = mfma16(al, br_, ar); ar = mfma16(ah, br_, ar);
      }
#pragma unroll
      for (int i = 0; i < 4; ++i){
        au[i] = fast_tanh(au[i] + bu1c + xr[i] * wu1L);
        ar[i] = fast_tanh(ar[i] + br1c + xr[i] * wr1L);
      }
#pragma unroll
      for (int i = 0; i < 4; ++i){
        LDSU[HB_O  + wr128[i]] = bf16r(au[i]);
        LDSU[SGH_O + wr128[i]] = bf16r(ar[i]);
      }
    }
    __syncthreads();
    // ---------------- GRU g2: second layers (mean->u from HB, std->r from SGH) ----------------
    f32x4 rr = {0.f,0.f,0.f,0.f};
    {
      f32x4 acc = {0.f,0.f,0.f,0.f};
      const int srcO = isMean ? HB_O : SGH_O;
      const int pb   = isMean ? OFF_WU2 : OFF_WR2;
#pragma unroll
      for (int ks = 0; ks < 4; ++ks)
        acc = mfma16(ldsA(LDSU, srcO + a128[ks]), load_bfrag(pack + pb, 4*(w & 3) + ks, lane), acc);
      if (isMean){
#pragma unroll
        for (int i = 0; i < 4; ++i){ u[i] = fast_sigmoid(acc[i] + g2b); FUR[FU_F + furi[i]] = u[i]; }
      } else {
#pragma unroll
        for (int i = 0; i < 4; ++i){ rr[i] = fast_sigmoid(acc[i] + g2b); FUR[FR_F + furi[i]] = rr[i]; }
      }
    }
    f32x4 mk;
#pragma unroll
    for (int i = 0; i < 4; ++i) mk[i] = mtr[(rowBase + rb + i) * T_LEN + tj];
    __syncthreads();
    // ---------------- GRU g3: gated state yc -> HB(hi)/SGH(lo) ----------------
    {
      f32x4 yc;
      if (isMean){
#pragma unroll
        for (int i = 0; i < 4; ++i){ float r_ = FUR[FR_F + furi[i]]; yc[i] = yf[i] * r_; }
      } else {
#pragma unroll
        for (int i = 0; i < 4; ++i){ u[i] = FUR[FU_F + furi[i]]; yc[i] = st[i] * rr[i]; }
      }
#pragma unroll
      for (int i = 0; i < 4; ++i){
        unsigned short hi = bf16r(yc[i]);
        LDSU[HB_O  + wr128[i]] = hi;
        LDSU[SGH_O + wr128[i]] = bf16r(yc[i] - bf16tof(hi));
      }
    }
    __syncthreads();
    // ---------------- GRU g4: n first layer (read HB/SGH, write HA) ----------------
    {
      f32x4 an = {0.f,0.f,0.f,0.f};
#pragma unroll
      for (int ks = 0; ks < 4; ++ks){
        bf16x8 ah = ldsA(LDSU, HB_O  + a128[ks]);
        bf16x8 al = ldsA(LDSU, SGH_O + a128[ks]);
        bf16x8 bn = load_bfrag(pack + OFF_WN1, 4*w + ks, lane);
        an = mfma16(al, bn, an); an = mfma16(ah, bn, an);
      }
#pragma unroll
      for (int i = 0; i < 4; ++i) an[i] = fast_tanh(an[i] + bn1c + xr[i] * wn1L);
#pragma unroll
      for (int i = 0; i < 4; ++i) LDSU[HA_O + wr128[i]] = bf16r(an[i]);
    }
    __syncthreads();
    // ---------------- GRU g5: n second layer + blend + write st-mean -> HB[16][64] ----------------
    {
      f32x4 ns = {0.f,0.f,0.f,0.f};
#pragma unroll
      for (int ks = 0; ks < 4; ++ks)
        ns = mfma16(ldsA(LDSU, HA_O + a128[ks]), load_bfrag(pack + OFF_WN2, 4*w + ks, lane), ns);
#pragma unroll
      for (int i = 0; i < 4; ++i){
        float nv = ns[i] + bn2c;
        float uu = u[i];
        float base = isMean ? yf[i] : st[i];
        float nm = (1.0f - uu) * nv + uu * base;
        float fs = mk[i] * nm + (1.0f - mk[i]) * base;
        st[i] = isMean ? fs : fabsf(fs);
      }
      if (isMean){
#pragma unroll
        for (int i = 0; i < 4; ++i) LDSU[HB_O + wr64[i]] = bf16r(st[i]);
      }
    }
    __syncthreads();
  }

  // ---------------- store ----------------
#pragma unroll
  for (int i = 0; i < 4; ++i){
    int r = rowBase + rb + i;
    if (isMean) out[r * 64 + c64] = st[i];
    else        out[524288 + r * 64 + c64] = st[i];
  }
}

extern "C" void kernel_launch(void* const* d_in, const int* in_sizes, int n_in,
                              void* d_out, int out_size, void* d_ws, size_t ws_size,
                              hipStream_t stream)
{
  (void)in_sizes; (void)n_in; (void)out_size; (void)ws_size;
  unsigned short* pack = (unsigned short*)d_ws;
  prep_pack<<<dim3((PREP_TOT + 255) / 256), dim3(256), 0, stream>>>(
      (const float*)d_in[2],  (const float*)d_in[4],  (const float*)d_in[6],
      (const float*)d_in[8],  (const float*)d_in[12], (const float*)d_in[16],
      (const float*)d_in[10], (const float*)d_in[14], (const float*)d_in[18],
      (const float*)d_in[7],  pack);
  ode_rnn_main<<<dim3(512), dim3(512), 0, stream>>>(
      (const float*)d_in[0],  (const float*)d_in[1],
      (const float*)d_in[3],  (const float*)d_in[5],  (const float*)d_in[7],
      (const float*)d_in[9],  (const float*)d_in[11],
      (const float*)d_in[13], (const float*)d_in[15],
      (const float*)d_in[17], (const float*)d_in[19],
      (const float*)d_in[8],  (const float*)d_in[12], (const float*)d_in[16],
      (const unsigned short*)pack, (float*)d_out);
}